// Round 8
// baseline (169.891 us; speedup 1.0000x reference)
//
#include <hip/hip_runtime.h>
#include <cfloat>
#include <climits>

#define B_DIM 16
#define C_DIM 64
#define N_DIM 2048
#define O_DIM 64
#define K_NN  3

typedef __attribute__((ext_vector_type(8))) short bf16x8;
typedef __attribute__((ext_vector_type(4))) float floatx4;

__device__ __forceinline__ unsigned short f32_to_bf16_rne(float f) {
  unsigned int u = __float_as_uint(f);
  return (unsigned short)((u + 0x7fffu + ((u >> 16) & 1u)) >> 16);
}
__device__ __forceinline__ float bf16_to_f32(unsigned short h) {
  return __uint_as_float(((unsigned int)h) << 16);
}

// Branchless fp32 top-4 insert (membership only; exact re-rank later).
__device__ __forceinline__ void ins4(float key, int jv, float* k, int* j) {
  bool c3 = key < k[3], c2 = key < k[2], c1 = key < k[1], c0 = key < k[0];
  k[3] = c2 ? k[2] : (c3 ? key : k[3]);
  j[3] = c2 ? j[2] : (c3 ? jv  : j[3]);
  k[2] = c1 ? k[1] : (c2 ? key : k[2]);
  j[2] = c1 ? j[1] : (c2 ? jv  : j[2]);
  k[1] = c0 ? k[0] : (c1 ? key : k[1]);
  j[1] = c0 ? j[0] : (c1 ? jv  : j[1]);
  k[0] = c0 ? key : k[0];
  j[0] = c0 ? jv  : j[0];
}

// ---- kernel 1: x -> xT fp32 [B][N][C], bf16 hi/lo split (chunk-swizzled
// in memory: 16B chunk q of row n stored at q^(n&7)), fp64+fp32 norms.
// Blocks >= 512 do the W transpose (fused to save a dispatch). ----
__global__ __launch_bounds__(256) void prep_kernel(
    const float* __restrict__ x, float* __restrict__ xT,
    unsigned short* __restrict__ xTh, unsigned short* __restrict__ xTl,
    double* __restrict__ nd, float* __restrict__ nf,
    const float* __restrict__ W, float* __restrict__ Wt) {
  int bid = blockIdx.x;
  int t = threadIdx.x;
  if (bid >= 512) {                  // W transpose: 48 blocks
    int t2 = (bid - 512) * 256 + t;  // 12288 = O * C * K
    int o  = t2 / (C_DIM * K_NN);
    int ck = t2 - o * (C_DIM * K_NN);
    Wt[ck * O_DIM + o] = W[t2];
    return;
  }
  __shared__ __align__(16) float xs[C_DIM][68];
  int b  = bid >> 5;
  int n0 = (bid & 31) * 64;
  const float* xb = x + (size_t)b * C_DIM * N_DIM;
  #pragma unroll
  for (int r = 0; r < 4; ++r) {
    int idx = r * 256 + t;           // 1024 float4 tasks
    int c = idx >> 4;
    int qq = idx & 15;
    *(float4*)&xs[c][qq * 4] = *(const float4*)(xb + (size_t)c * N_DIM + n0 + qq * 4);
  }
  __syncthreads();
  int n = t >> 2, cg = t & 3;        // 64 n x 4 c-groups of 16
  float v[16];
  #pragma unroll
  for (int cc = 0; cc < 16; ++cc) v[cc] = xs[cg * 16 + cc][n];
  double ps = 0.0;
  #pragma unroll
  for (int cc = 0; cc < 16; ++cc) ps = fma((double)v[cc], (double)v[cc], ps);
  ps += __shfl_xor(ps, 1, 64);
  ps += __shfl_xor(ps, 2, 64);       // lanes t^1,t^2 share n
  size_t row = (size_t)b * N_DIM + n0 + n;
  #pragma unroll
  for (int qq = 0; qq < 4; ++qq) {
    float4 wv; wv.x = v[qq*4]; wv.y = v[qq*4+1]; wv.z = v[qq*4+2]; wv.w = v[qq*4+3];
    *(float4*)&xT[row * C_DIM + cg * 16 + qq * 4] = wv;
  }
  unsigned short hh[16], ll[16];
  #pragma unroll
  for (int cc = 0; cc < 16; ++cc) {
    hh[cc] = f32_to_bf16_rne(v[cc]);
    ll[cc] = f32_to_bf16_rne(v[cc] - bf16_to_f32(hh[cc]));
  }
  #pragma unroll
  for (int e = 0; e < 2; ++e) {
    int phys = (2 * cg + e) ^ (n & 7);
    unsigned int hp[4], lp[4];
    #pragma unroll
    for (int xk = 0; xk < 4; ++xk) {
      hp[xk] = (unsigned)hh[e*8 + 2*xk] | ((unsigned)hh[e*8 + 2*xk + 1] << 16);
      lp[xk] = (unsigned)ll[e*8 + 2*xk] | ((unsigned)ll[e*8 + 2*xk + 1] << 16);
    }
    ((uint4*)xTh)[row * 8 + phys] = *(uint4*)hp;
    ((uint4*)xTl)[row * 8 + phys] = *(uint4*)lp;
  }
  if (cg == 0) {
    nd[row] = ps;
    nf[row] = (float)ps;
  }
}

// ---- kernel 2: split-bf16 MFMA distance sweep ----
// grid = B*32*4 = 2048 blocks (64-wide itile x j-quarter), 256 thr (4 waves).
// A-operand = J-tile (LDS, 32KB), B-operand = I-frags (registers).
// launch_bounds(256,5): 5 blocks/CU (LDS 5x32KB = 160KB exactly), VGPR<=102.
__global__ __launch_bounds__(256, 5) void topk_kernel(
    const unsigned short* __restrict__ xTh, const unsigned short* __restrict__ xTl,
    const float* __restrict__ nf, int* __restrict__ cand) {
  __shared__ __align__(16) unsigned short Jh[128 * 64];  // 16 KB
  __shared__ __align__(16) unsigned short Jl[128 * 64];  // 16 KB
  int bid   = blockIdx.x;
  int q     = bid & 3;               // j-quarter
  int itile = (bid >> 2) & 31;       // 32 i-tiles of 64 rows
  int b     = bid >> 7;
  int i0    = itile * 64;
  int jq0   = q * 512;
  int t = threadIdx.x;
  int w = t >> 6, lane = t & 63, quad = lane >> 4, col = lane & 15;
  int csw = col & 7;
  const unsigned short* xh = xTh + (size_t)b * N_DIM * 64;
  const unsigned short* xl = xTl + (size_t)b * N_DIM * 64;
  const float* nfb = nf + b * N_DIM;

  // I-frags (B operand) once from global. row&7 == col&7 == csw.
  bf16x8 ih[2], il[2];               // [ks]
  #pragma unroll
  for (int ks = 0; ks < 2; ++ks) {
    size_t row = i0 + w * 16 + col;
    int phys = (ks * 4 + quad) ^ csw;
    ih[ks] = *(const bf16x8*)(xh + row * 64 + phys * 8);
    il[ks] = *(const bf16x8*)(xl + row * 64 + phys * 8);
  }

  float ck[4]; int cj[4];
  #pragma unroll
  for (int s = 0; s < 4; ++s) { ck[s] = FLT_MAX; cj[s] = 0; }

  int a0 = col * 64 + ((quad ^ csw) * 8);        // ks=0 frag offset (shorts)
  int a1 = col * 64 + (((4 + quad) ^ csw) * 8);  // ks=1

  for (int js = 0; js < 4; ++js) {
    int j0 = jq0 + js * 128;
    __syncthreads();                 // prior frag reads done before overwrite
    {
      // stage 32 j-rows (Jh+Jl) per wave: pure 16B copies, layout verbatim
      const unsigned short* sh = xh + (size_t)(j0 + w * 32) * 64;
      const unsigned short* sl = xl + (size_t)(j0 + w * 32) * 64;
      unsigned short* dh = &Jh[w * 32 * 64];
      unsigned short* dl = &Jl[w * 32 * 64];
      int off = lane * 8;
      #pragma unroll
      for (int k2 = 0; k2 < 4; ++k2) {
        *(uint4*)(dh + k2 * 512 + off) = *(const uint4*)(sh + k2 * 512 + off);
        *(uint4*)(dl + k2 * 512 + off) = *(const uint4*)(sl + k2 * 512 + off);
      }
    }
    __syncthreads();

    floatx4 acc[8];
    #pragma unroll
    for (int jt = 0; jt < 8; ++jt) acc[jt] = (floatx4){0.f, 0.f, 0.f, 0.f};

    #pragma unroll
    for (int ks = 0; ks < 2; ++ks) {
      int ab = ks ? a1 : a0;
      #pragma unroll
      for (int jt = 0; jt < 8; ++jt) {
        bf16x8 jh = *(const bf16x8*)&Jh[jt * 1024 + ab];
        bf16x8 jl = *(const bf16x8*)&Jl[jt * 1024 + ab];
        acc[jt] = __builtin_amdgcn_mfma_f32_16x16x32_bf16(jl, ih[ks], acc[jt], 0, 0, 0);
        acc[jt] = __builtin_amdgcn_mfma_f32_16x16x32_bf16(jh, il[ks], acc[jt], 0, 0, 0);
        acc[jt] = __builtin_amdgcn_mfma_f32_16x16x32_bf16(jh, ih[ks], acc[jt], 0, 0, 0);
      }
    }

    // epilogue: key = nf[j] - 2*dot; j = j0 + jt*16 + quad*4 + r
    int jb = j0 + quad * 4;
    #pragma unroll
    for (int jt = 0; jt < 8; ++jt) {
      float4 nv = *(const float4*)(nfb + jb + jt * 16);
      float nfa[4] = {nv.x, nv.y, nv.z, nv.w};
      #pragma unroll
      for (int r = 0; r < 4; ++r) {
        float key = fmaf(-2.0f, acc[jt][r], nfa[r]);
        int jv = jb + jt * 16 + r;
        ins4(key, jv, ck, cj);
      }
    }
  }

  // merge across the 4 quads holding the same col (= same i-row)
  #pragma unroll
  for (int m = 16; m < 64; m <<= 1) {
    float tk[4]; int tj[4];
    #pragma unroll
    for (int s = 0; s < 4; ++s) {
      tk[s] = __shfl_xor(ck[s], m, 64);
      tj[s] = __shfl_xor(cj[s], m, 64);
    }
    #pragma unroll
    for (int s = 0; s < 4; ++s) ins4(tk[s], tj[s], ck, cj);
  }
  if (quad == 0) {
    int row = b * N_DIM + i0 + w * 16 + col;
    int base = row * 16 + q * 4;
    #pragma unroll
    for (int s = 0; s < 4; ++s) cand[base + s] = cj[s];
  }
}

// ---- kernel 2b: exact fp64 re-rank via order-isomorphic u64 pack ----
// dist_sq + 1 > 0, so its fp64 bit pattern compares as u64. Pack
// (bits & ~2047) | j -> lexicographic (dist, j) in ONE u64; top-3 =
// 3-pass masked min butterfly (4 shfl levels, u64 min) instead of the
// r7 fp64 insert3d chains (~2500 cyc/wave -> ~300). Quantization zone
// (true gaps < 2^-41-relative ~ 2e-10) is measure-zero for random data.
// Wave per row; lane = cand(16) x seg(4). grid = (B*N)/4 = 8192.
__global__ __launch_bounds__(256) void refine_kernel(
    const float* __restrict__ xT, const double* __restrict__ nd,
    const int* __restrict__ cand, int* __restrict__ topk) {
  int t = threadIdx.x;
  int lane = t & 63;
  int row = blockIdx.x * 4 + (t >> 6);   // [0, B*N)
  int b = row >> 11;
  int n = row & (N_DIM - 1);
  int cid = lane >> 2;
  int seg = lane & 3;
  int j = cand[row * 16 + cid];
  const float* xn = xT + (((size_t)b * N_DIM + n) * C_DIM) + seg * 16;
  const float* xj = xT + (((size_t)b * N_DIM + j) * C_DIM) + seg * 16;
  double dot = 0.0;
  #pragma unroll
  for (int qq = 0; qq < 4; ++qq) {
    float4 a  = *(const float4*)(xn + qq * 4);
    float4 bb = *(const float4*)(xj + qq * 4);
    dot = fma((double)a.x, (double)bb.x, dot);
    dot = fma((double)a.y, (double)bb.y, dot);
    dot = fma((double)a.z, (double)bb.z, dot);
    dot = fma((double)a.w, (double)bb.w, dot);
  }
  dot += __shfl_xor(dot, 1, 64);     // reduce over seg (lanes ^1, ^2)
  dot += __shfl_xor(dot, 2, 64);
  // full dist_sq + 1 (adding nd[n] is rank-preserving; +1 ensures > 0)
  double key = fma(-2.0, dot, nd[b * N_DIM + j] + nd[b * N_DIM + n]) + 1.0;
  unsigned long long u =
      ((unsigned long long)__double_as_longlong(key) & ~2047ull) |
      (unsigned long long)(unsigned)j;
  // 3-pass masked min over the 16 cand groups (masks 1,2 are dup copies)
  unsigned long long v = u;
  int jout[3];
  #pragma unroll
  for (int p = 0; p < 3; ++p) {
    unsigned long long m = v;
    #pragma unroll
    for (int msk = 4; msk < 64; msk <<= 1) {
      unsigned long long o = __shfl_xor(m, msk, 64);
      m = (o < m) ? o : m;
    }
    jout[p] = (int)(m & 2047ull);
    v = (v == m) ? ~0ull : v;        // mask winner (and its seg copies)
  }
  if (lane == 0) {
    int base = row * K_NN;
    topk[base + 0] = jout[0];
    topk[base + 1] = jout[1];
    topk[base + 2] = jout[2];
  }
}

// ---- kernel 3: gather neighbors (coalesced via xT) + conv ----
#define NT   64
#define NPAD 68
__global__ __launch_bounds__(256) void conv_kernel(
    const float* __restrict__ xT, const float* __restrict__ Wt,
    const float* __restrict__ bias, const int* __restrict__ topk,
    float* __restrict__ out) {
  __shared__ __align__(16) float nb[C_DIM * K_NN][NPAD];  // 52224 B
  int bid = blockIdx.x;
  int b  = bid >> 5;
  int n0 = (bid & 31) * NT;
  const float* xtb = xT + (size_t)b * N_DIM * C_DIM;
  const int* tk = topk + (b * N_DIM + n0) * K_NN;
  int t = threadIdx.x;

  #pragma unroll
  for (int p = 0; p < 12; ++p) {
    int u = p * 256 + t;            // 3072 tasks: 192 rows x 16 segs
    int seg = u & 15;
    int r   = u >> 4;               // r = k*64 + n
    int k = r >> 6, n = r & 63;
    int j = tk[n * K_NN + k];
    float4 v = *(const float4*)(xtb + (size_t)j * C_DIM + seg * 4);
    nb[(seg * 4 + 0) * 3 + k][n] = v.x;
    nb[(seg * 4 + 1) * 3 + k][n] = v.y;
    nb[(seg * 4 + 2) * 3 + k][n] = v.z;
    nb[(seg * 4 + 3) * 3 + k][n] = v.w;
  }
  __syncthreads();

  int ng = t & 15, og = t >> 4;
  float acc[4][4];
  #pragma unroll
  for (int oo = 0; oo < 4; ++oo) {
    float bv = bias[(og << 2) + oo];
    #pragma unroll
    for (int nn = 0; nn < 4; ++nn) acc[oo][nn] = bv;
  }
  const float* nbp = &nb[0][0] + (ng << 2);
  const float* wtp = Wt + (og << 2);
  #pragma unroll 4
  for (int ckk = 0; ckk < C_DIM * K_NN; ++ckk) {
    float4 nv = *(const float4*)(nbp + ckk * NPAD);
    float4 wv = *(const float4*)(wtp + ckk * O_DIM);
    float na[4] = {nv.x, nv.y, nv.z, nv.w};
    float wa[4] = {wv.x, wv.y, wv.z, wv.w};
    #pragma unroll
    for (int oo = 0; oo < 4; ++oo)
      #pragma unroll
      for (int nn = 0; nn < 4; ++nn)
        acc[oo][nn] = fmaf(wa[oo], na[nn], acc[oo][nn]);
  }
  #pragma unroll
  for (int oo = 0; oo < 4; ++oo) {
    int o = (og << 2) + oo;
    float4 v; v.x = acc[oo][0]; v.y = acc[oo][1]; v.z = acc[oo][2]; v.w = acc[oo][3];
    *(float4*)&out[(size_t)(b * O_DIM + o) * N_DIM + n0 + (ng << 2)] = v;
  }
}

extern "C" void kernel_launch(void* const* d_in, const int* in_sizes, int n_in,
                              void* d_out, int out_size, void* d_ws, size_t ws_size,
                              hipStream_t stream) {
  const float* x    = (const float*)d_in[0];   // [B][C][N]
  const float* W    = (const float*)d_in[1];   // [O][C][K]
  const float* bias = (const float*)d_in[2];   // [O]
  float* out = (float*)d_out;                  // [B][O][N]
  char* ws = (char*)d_ws;
  // ws layout (bytes):
  //   xT   fp32  [B][N][C]          @ 0         (8 MB)
  //   xTh  bf16  [B][N][C] swizzled @ 8388608   (4 MB)
  //   xTl  bf16  [B][N][C] swizzled @ 12582912  (4 MB)
  //   nd   fp64  [B*N]              @ 16777216  (256 KB)
  //   nf   fp32  [B*N]              @ 17039360  (128 KB)
  //   cand int   [B*N][16]          @ 17170432  (2 MB)
  //   topk int   [B*N][3]           @ 19267584  (384 KB)
  //   Wt   fp32  [C*K][O]           @ 19660800  (48 KB)
  float*          xT  = (float*)ws;
  unsigned short* xTh = (unsigned short*)(ws + 8388608);
  unsigned short* xTl = (unsigned short*)(ws + 12582912);
  double*         nd  = (double*)(ws + 16777216);
  float*          nfp = (float*)(ws + 17039360);
  int*            cd  = (int*)(ws + 17170432);
  int*            tk  = (int*)(ws + 19267584);
  float*          Wt  = (float*)(ws + 19660800);

  prep_kernel<<<512 + 48, 256, 0, stream>>>(x, xT, xTh, xTl, nd, nfp, W, Wt);
  topk_kernel<<<B_DIM * 32 * 4, 256, 0, stream>>>(xTh, xTl, nfp, cd);
  refine_kernel<<<(B_DIM * N_DIM) / 4, 256, 0, stream>>>(xT, nd, cd, tk);
  conv_kernel<<<B_DIM * (N_DIM / NT), 256, 0, stream>>>(xT, Wt, bias, tk, out);
}